// Round 1
// baseline (1388.385 us; speedup 1.0000x reference)
//
#include <hip/hip_runtime.h>

#define K_CODES 1024
#define DIM 64
#define B_ 16
#define T_ 8192
#define N_ (B_*T_)          // 131072 vectors
#define EPSF 1e-5f

// ---------------- prep: fp32 embeddings -> fp64 table + fp64 norms ----------
__global__ __launch_bounds__(64) void vq_prep(const float* __restrict__ emb,
                                              double* __restrict__ e64,
                                              double* __restrict__ enorm64) {
    const int k = blockIdx.x;
    const int d = threadIdx.x;
    const float e = emb[k * DIM + d];
    const double ed = (double)e;
    e64[k * DIM + d] = ed;
    double s = ed * ed;
    #pragma unroll
    for (int off = 32; off; off >>= 1) s += __shfl_down(s, off, 64);
    if (d == 0) enorm64[k] = s;
}

// ---------------- main: argmin over K in fp64, fused outputs ----------------
__global__ __launch_bounds__(256, 2) void vq_main(const float* __restrict__ x,
                                                  const float* __restrict__ emb,
                                                  const double* __restrict__ e64,
                                                  const double* __restrict__ enorm64,
                                                  float* __restrict__ out,
                                                  float* __restrict__ dw,
                                                  int* __restrict__ counts) {
    const int v = blockIdx.x * 256 + threadIdx.x;
    const int b = v >> 13;            // T = 8192 = 2^13
    const int t = v & (T_ - 1);

    // x[b][d][t]: per-d loads are coalesced across the wave (lane <-> t)
    const float* xp = x + ((size_t)b << 19) + t;
    double xv[DIM];
    #pragma unroll
    for (int d = 0; d < DIM; d++) xv[d] = (double)xp[(size_t)d << 13];

    __shared__ double se[64 * DIM];   // 32 KiB tile: 64 codes x 64 dims
    __shared__ double sn[64];

    double best = 1e300;
    int bidx = 0;

    for (int k0 = 0; k0 < K_CODES; k0 += 64) {
        __syncthreads();
        #pragma unroll
        for (int i = 0; i < 16; i++)
            se[threadIdx.x + i * 256] = e64[(size_t)k0 * DIM + threadIdx.x + i * 256];
        if (threadIdx.x < 64) sn[threadIdx.x] = enorm64[k0 + threadIdx.x];
        __syncthreads();

        for (int kk = 0; kk < 64; kk++) {
            const double* ek = &se[kk * DIM];
            double a0 = 0.0, a1 = 0.0, a2 = 0.0, a3 = 0.0;
            #pragma unroll
            for (int d = 0; d < DIM; d += 4) {
                a0 = __fma_rn(xv[d + 0], ek[d + 0], a0);
                a1 = __fma_rn(xv[d + 1], ek[d + 1], a1);
                a2 = __fma_rn(xv[d + 2], ek[d + 2], a2);
                a3 = __fma_rn(xv[d + 3], ek[d + 3], a3);
            }
            const double dist = sn[kk] - 2.0 * ((a0 + a1) + (a2 + a3));
            if (dist < best) { best = dist; bidx = k0 + kk; }  // first-min tie rule
        }
    }

    // quantized output, mimicking reference's fp32  x + (q - x)
    const float* eq = emb + bidx * DIM;
    float* op = out + ((size_t)b << 19) + t;
    #pragma unroll
    for (int d = 0; d < DIM; d++) {
        const float xf = (float)xv[d];
        const float q  = eq[d];
        op[(size_t)d << 13] = xf + (q - xf);   // per-d coalesced store
    }

    // EMA accumulators
    atomicAdd(&counts[bidx], 1);
    float* dwp = dw + bidx * DIM;
    #pragma unroll
    for (int d = 0; d < DIM; d++) atomicAdd(&dwp[d], (float)xv[d]);
}

// ---------------- finalize: new_embeddings = dw / cluster_size --------------
__global__ __launch_bounds__(64) void vq_final(const float* __restrict__ dw,
                                               const int* __restrict__ counts,
                                               float* __restrict__ newemb) {
    const int k = blockIdx.x;
    const int d = threadIdx.x;
    const float c = (float)counts[k];
    const float n = 131072.0f;
    const float cluster = (c + EPSF) / (n + 1024.0f * EPSF) * n;
    newemb[k * DIM + d] = dw[k * DIM + d] / cluster;
}

extern "C" void kernel_launch(void* const* d_in, const int* in_sizes, int n_in,
                              void* d_out, int out_size, void* d_ws, size_t ws_size,
                              hipStream_t stream) {
    const float* x   = (const float*)d_in[0];
    const float* emb = (const float*)d_in[1];

    char* ws = (char*)d_ws;
    double* e64     = (double*)ws;                   // 512 KiB
    double* enorm64 = (double*)(ws + 512 * 1024);    //   8 KiB
    float*  dw      = (float*)(ws + 520 * 1024);     // 256 KiB
    int*    counts  = (int*)(ws + 776 * 1024);       //   4 KiB

    float* out    = (float*)d_out;
    float* newemb = out + (size_t)B_ * DIM * T_;

    // zero EMA accumulators every launch (ws is poisoned once, never restored)
    hipMemsetAsync(dw, 0, (size_t)K_CODES * DIM * sizeof(float) + K_CODES * sizeof(int), stream);

    vq_prep<<<K_CODES, 64, 0, stream>>>(emb, e64, enorm64);
    vq_main<<<N_ / 256, 256, 0, stream>>>(x, emb, e64, enorm64, out, dw, counts);
    vq_final<<<K_CODES, 64, 0, stream>>>(dw, counts, newemb);
}

// Round 2
// 1280.665 us; speedup vs baseline: 1.0841x; 1.0841x over previous
//
#include <hip/hip_runtime.h>

#define K_CODES 1024
#define DIM 64
#define B_ 16
#define T_ 8192
#define N_ (B_*T_)          // 131072 vectors
#define EPSF 1e-5f
#define MARGIN 7.5e-5f

// ---------------- prep: fp32 embeddings -> fp64 table + fp64 norms ----------
__global__ __launch_bounds__(64) void vq_prep(const float* __restrict__ emb,
                                              double* __restrict__ e64,
                                              double* __restrict__ enorm64) {
    const int k = blockIdx.x;
    const int d = threadIdx.x;
    const double ed = (double)emb[k * DIM + d];
    e64[k * DIM + d] = ed;
    double s = ed * ed;
    #pragma unroll
    for (int off = 32; off; off >>= 1) s += __shfl_down(s, off, 64);
    if (d == 0) enorm64[k] = s;
}

// ---------------- screen: fp32 top-2 argmin, 2 threads per vector -----------
__global__ __launch_bounds__(256) void vq_screen(const float* __restrict__ x,
                                                 const float* __restrict__ emb,
                                                 const double* __restrict__ enorm64,
                                                 float* __restrict__ out,
                                                 float* __restrict__ dw,
                                                 int* __restrict__ counts,
                                                 int* __restrict__ flagcnt,
                                                 int* __restrict__ flagids) {
    const int gtid  = blockIdx.x * 256 + threadIdx.x;   // 0 .. 2N-1
    const int v     = gtid >> 1;
    const int dhalf = gtid & 1;                          // which 32-dim half
    const int b     = v >> 13;                           // T = 8192
    const int t     = v & (T_ - 1);

    // x[b][dhalf*32 + j][t]; consecutive lanes alternate halves, coalesced per stream
    const float* xp = x + ((size_t)b << 19) + ((size_t)dhalf << 18) + t;
    float xv[32];
    #pragma unroll
    for (int j = 0; j < 32; j++) xv[j] = xp[(size_t)j << 13];

    __shared__ float se[64 * DIM];    // 16 KiB: 64 codes x 64 dims
    __shared__ float sn[64];

    float best1 = 1e30f, best2 = 1e30f;
    int bidx = 0;

    for (int k0 = 0; k0 < K_CODES; k0 += 64) {
        __syncthreads();
        #pragma unroll
        for (int i = 0; i < 16; i++)
            se[threadIdx.x + i * 256] = emb[(size_t)k0 * DIM + threadIdx.x + i * 256];
        if (threadIdx.x < 64) sn[threadIdx.x] = (float)enorm64[k0 + threadIdx.x];
        __syncthreads();

        for (int kk = 0; kk < 64; kk++) {
            const float* ek = &se[kk * DIM + dhalf * 32];
            float a0 = 0.f, a1 = 0.f, a2 = 0.f, a3 = 0.f;
            #pragma unroll
            for (int j = 0; j < 32; j += 4) {
                a0 = __fmaf_rn(xv[j + 0], ek[j + 0], a0);
                a1 = __fmaf_rn(xv[j + 1], ek[j + 1], a1);
                a2 = __fmaf_rn(xv[j + 2], ek[j + 2], a2);
                a3 = __fmaf_rn(xv[j + 3], ek[j + 3], a3);
            }
            const float part = (a0 + a1) + (a2 + a3);
            const float dot  = part + __shfl_xor(part, 1, 64);  // both halves
            const float dist = sn[kk] - 2.0f * dot;
            if (dist < best1) { best2 = best1; best1 = dist; bidx = k0 + kk; }
            else if (dist < best2) { best2 = dist; }
        }
    }

    if (best2 - best1 <= MARGIN) {
        // ambiguous at fp32 precision -> defer to exact fp64 rescan
        if (dhalf == 0) {
            const int pos = atomicAdd(flagcnt, 1);
            flagids[pos] = v;
        }
    } else {
        // certain: fused epilogue for this thread's 32 dims
        const float* eq = emb + bidx * DIM + dhalf * 32;
        float* op = out + ((size_t)b << 19) + ((size_t)dhalf << 18) + t;
        #pragma unroll
        for (int j = 0; j < 32; j++) {
            const float xf = xv[j];
            op[(size_t)j << 13] = xf + (eq[j] - xf);   // reference's fp32 x+(q-x)
        }
        if (dhalf == 0) atomicAdd(&counts[bidx], 1);
        float* dwp = dw + bidx * DIM + dhalf * 32;
        #pragma unroll
        for (int j = 0; j < 32; j++) atomicAdd(&dwp[j], xv[j]);
    }
}

// ---------------- rescan: exact fp64 argmin for flagged vectors -------------
__global__ __launch_bounds__(256) void vq_rescan(const float* __restrict__ x,
                                                 const float* __restrict__ emb,
                                                 const double* __restrict__ e64,
                                                 const double* __restrict__ enorm64,
                                                 float* __restrict__ out,
                                                 float* __restrict__ dw,
                                                 int* __restrict__ counts,
                                                 const int* __restrict__ flagcnt,
                                                 const int* __restrict__ flagids) {
    __shared__ double se[64 * DIM];   // 32 KiB: 64 codes x 64 dims fp64
    __shared__ double sn[64];

    const int count = *flagcnt;
    const int vloc = threadIdx.x >> 2;   // 0..63 : vector slot in block
    const int dg   = threadIdx.x & 3;    // 0..3  : 16-dim group

    for (int base = blockIdx.x * 64; base < count; base += gridDim.x * 64) {
        const bool active = (base + vloc) < count;
        const int v = active ? flagids[base + vloc] : 0;
        const int b = v >> 13;
        const int t = v & (T_ - 1);

        double xv[16];
        if (active) {
            const float* xp = x + ((size_t)b << 19) + ((size_t)(dg * 16) << 13) + t;
            #pragma unroll
            for (int j = 0; j < 16; j++) xv[j] = (double)xp[(size_t)j << 13];
        } else {
            #pragma unroll
            for (int j = 0; j < 16; j++) xv[j] = 0.0;
        }

        double best = 1e300;
        int bidx = 0;

        for (int k0 = 0; k0 < K_CODES; k0 += 64) {
            __syncthreads();
            #pragma unroll
            for (int i = 0; i < 16; i++)
                se[threadIdx.x + i * 256] = e64[(size_t)k0 * DIM + threadIdx.x + i * 256];
            if (threadIdx.x < 64) sn[threadIdx.x] = enorm64[k0 + threadIdx.x];
            __syncthreads();

            for (int kk = 0; kk < 64; kk++) {
                const double* ek = &se[kk * DIM + dg * 16];
                double a0 = 0.0, a1 = 0.0, a2 = 0.0, a3 = 0.0;
                #pragma unroll
                for (int j = 0; j < 16; j += 4) {
                    a0 = __fma_rn(xv[j + 0], ek[j + 0], a0);
                    a1 = __fma_rn(xv[j + 1], ek[j + 1], a1);
                    a2 = __fma_rn(xv[j + 2], ek[j + 2], a2);
                    a3 = __fma_rn(xv[j + 3], ek[j + 3], a3);
                }
                double p = (a0 + a1) + (a2 + a3);
                p += __shfl_xor(p, 1, 64);     // sum 4 dim-groups (lanes differ in bits 0-1)
                p += __shfl_xor(p, 2, 64);
                const double dist = sn[kk] - 2.0 * p;
                if (dist < best) { best = dist; bidx = k0 + kk; }  // first-min tie rule
            }
        }

        if (active) {
            const float* eq = emb + bidx * DIM + dg * 16;
            float* op = out + ((size_t)b << 19) + ((size_t)(dg * 16) << 13) + t;
            #pragma unroll
            for (int j = 0; j < 16; j++) {
                const float xf = (float)xv[j];
                op[(size_t)j << 13] = xf + (eq[j] - xf);
            }
            if (dg == 0) atomicAdd(&counts[bidx], 1);
            float* dwp = dw + bidx * DIM + dg * 16;
            #pragma unroll
            for (int j = 0; j < 16; j++) atomicAdd(&dwp[j], (float)xv[j]);
        }
    }
}

// ---------------- finalize: new_embeddings = dw / cluster_size --------------
__global__ __launch_bounds__(64) void vq_final(const float* __restrict__ dw,
                                               const int* __restrict__ counts,
                                               float* __restrict__ newemb) {
    const int k = blockIdx.x;
    const int d = threadIdx.x;
    const float c = (float)counts[k];
    const float n = 131072.0f;
    const float cluster = (c + EPSF) / (n + 1024.0f * EPSF) * n;
    newemb[k * DIM + d] = dw[k * DIM + d] / cluster;
}

extern "C" void kernel_launch(void* const* d_in, const int* in_sizes, int n_in,
                              void* d_out, int out_size, void* d_ws, size_t ws_size,
                              hipStream_t stream) {
    const float* x   = (const float*)d_in[0];
    const float* emb = (const float*)d_in[1];

    char* ws = (char*)d_ws;
    double* e64     = (double*)(ws);                 // 512 KiB
    double* enorm64 = (double*)(ws + 524288);        //   8 KiB
    float*  dw      = (float*)(ws + 532480);         // 256 KiB
    int*    counts  = (int*)(ws + 794624);           //   4 KiB
    int*    flagcnt = (int*)(ws + 798720);           //  64 B
    int*    flagids = (int*)(ws + 798784);           // 512 KiB

    float* out    = (float*)d_out;
    float* newemb = out + (size_t)B_ * DIM * T_;

    // zero dw + counts + flagcnt every launch (contiguous region)
    hipMemsetAsync(dw, 0, 262144 + 4096 + 64, stream);

    vq_prep<<<K_CODES, 64, 0, stream>>>(emb, e64, enorm64);
    vq_screen<<<(2 * N_) / 256, 256, 0, stream>>>(x, emb, enorm64, out, dw, counts,
                                                  flagcnt, flagids);
    vq_rescan<<<256, 256, 0, stream>>>(x, emb, e64, enorm64, out, dw, counts,
                                       flagcnt, flagids);
    vq_final<<<K_CODES, 64, 0, stream>>>(dw, counts, newemb);
}

// Round 3
// 838.292 us; speedup vs baseline: 1.6562x; 1.5277x over previous
//
#include <hip/hip_runtime.h>

#define K_CODES 1024
#define DIM 64
#define B_ 16
#define T_ 8192
#define N_ (B_*T_)          // 131072 vectors
#define EPSF 1e-5f
#define SMARGIN 3.75e-5f    // score-space margin == 7.5e-5 distance margin

// DPP quad_perm add: xor1 = [1,0,3,2] = 0xB1, xor2 = [2,3,0,1] = 0x4E
#define DPP_ADD(v, CTRL) \
    ((v) + __int_as_float(__builtin_amdgcn_update_dpp( \
        0, __float_as_int(v), (CTRL), 0xF, 0xF, true)))

// ---------------- prep: e -> fp64 table, half-norms in fp64 + fp32 ----------
__global__ __launch_bounds__(64) void vq_prep(const float* __restrict__ emb,
                                              double* __restrict__ e64,
                                              double* __restrict__ snh64,
                                              float* __restrict__ snh32) {
    const int k = blockIdx.x;
    const int d = threadIdx.x;
    const double ed = (double)emb[k * DIM + d];
    e64[k * DIM + d] = ed;
    double s = ed * ed;
    #pragma unroll
    for (int off = 32; off; off >>= 1) s += __shfl_down(s, off, 64);
    if (d == 0) { snh64[k] = 0.5 * s; snh32[k] = (float)(0.5 * s); }
}

// ---------------- screen: fp32 top-2, 4 thr/vec x VX=4, k-split block -------
__global__ __launch_bounds__(256, 2) void vq_screen(const float* __restrict__ x,
                                                    const float* __restrict__ emb,
                                                    const float* __restrict__ snh32,
                                                    float* __restrict__ out,
                                                    float* __restrict__ dw,
                                                    int* __restrict__ counts,
                                                    int* __restrict__ flagcnt,
                                                    int* __restrict__ flagids) {
    __shared__ float se[2][64 * DIM];   // per code-half: 64 codes x 64 dims
    __shared__ float ssnh[2][64];

    const int tid   = threadIdx.x;
    const int kh    = tid >> 7;          // code half (waves 0,1 -> 0; 2,3 -> 1)
    const int hid   = tid & 127;         // id within half
    const int lane  = tid & 63;
    const int vgrp  = (tid >> 6) & 1;    // 64-vector group within block
    const int vslot = lane >> 2;         // 0..15
    const int dg    = lane & 3;          // 16-dim group

    const int blk = blockIdx.x;          // 1024 blocks x 128 vectors
    const int b   = blk >> 6;            // 64 blocks per batch row
    const int tb  = (blk & 63) << 7;
    const int toff = tb + vgrp * 64 + vslot;      // + vx*16
    const float* xb = x + ((size_t)b << 19);

    float xv[4][16];
    #pragma unroll
    for (int vx = 0; vx < 4; vx++)
        #pragma unroll
        for (int j = 0; j < 16; j++)
            xv[vx][j] = xb[((size_t)(dg * 16 + j) << 13) + toff + vx * 16];

    float b1[4], b2[4]; int bi[4];
    #pragma unroll
    for (int vx = 0; vx < 4; vx++) { b1[vx] = -1e30f; b2[vx] = -1e30f; bi[vx] = 0; }

    for (int kt = 0; kt < 8; kt++) {
        const int k0 = (kh << 9) + (kt << 6);
        __syncthreads();
        #pragma unroll
        for (int i = 0; i < 32; i++)
            se[kh][hid + i * 128] = emb[k0 * DIM + hid + i * 128];
        if (hid < 64) ssnh[kh][hid] = snh32[k0 + hid];
        __syncthreads();

        #pragma unroll 4
        for (int kk = 0; kk < 64; kk++) {
            const float4* ep = (const float4*)&se[kh][kk * DIM + dg * 16];
            const float4 e0 = ep[0], e1 = ep[1], e2 = ep[2], e3 = ep[3];
            const float snh = ssnh[kh][kk];
            #pragma unroll
            for (int vx = 0; vx < 4; vx++) {
                float a = xv[vx][0] * e0.x;
                a = __fmaf_rn(xv[vx][1],  e0.y, a);
                a = __fmaf_rn(xv[vx][2],  e0.z, a);
                a = __fmaf_rn(xv[vx][3],  e0.w, a);
                a = __fmaf_rn(xv[vx][4],  e1.x, a);
                a = __fmaf_rn(xv[vx][5],  e1.y, a);
                a = __fmaf_rn(xv[vx][6],  e1.z, a);
                a = __fmaf_rn(xv[vx][7],  e1.w, a);
                a = __fmaf_rn(xv[vx][8],  e2.x, a);
                a = __fmaf_rn(xv[vx][9],  e2.y, a);
                a = __fmaf_rn(xv[vx][10], e2.z, a);
                a = __fmaf_rn(xv[vx][11], e2.w, a);
                a = __fmaf_rn(xv[vx][12], e3.x, a);
                a = __fmaf_rn(xv[vx][13], e3.y, a);
                a = __fmaf_rn(xv[vx][14], e3.z, a);
                a = __fmaf_rn(xv[vx][15], e3.w, a);
                a = DPP_ADD(a, 0xB1);    // + lane^1 partial
                a = DPP_ADD(a, 0x4E);    // + lane^2 partial -> full dot
                const float m = a - snh;
                b2[vx] = fmaxf(b2[vx], fminf(b1[vx], m));
                if (m > b1[vx]) { b1[vx] = m; bi[vx] = k0 + kk; }
            }
        }
    }

    // ---- merge the two code-halves through LDS (reuse se as scratch) ----
    __syncthreads();
    float* redS = (float*)&se[0][0];     // [2][128][4] floats
    const int vloc0 = vgrp * 64 + vslot;
    if (dg == 0) {
        #pragma unroll
        for (int vx = 0; vx < 4; vx++) {
            const int base = ((kh << 7) + vloc0 + vx * 16) * 4;
            redS[base]     = b1[vx];
            redS[base + 1] = b2[vx];
            redS[base + 2] = __int_as_float(bi[vx]);
        }
    }
    __syncthreads();

    if (kh == 0) {
        #pragma unroll
        for (int vx = 0; vx < 4; vx++) {
            const int vloc  = vloc0 + vx * 16;
            const int obase = (128 + vloc) * 4;
            const float ob1 = redS[obase];
            const float ob2 = redS[obase + 1];
            const int   oi  = __float_as_int(redS[obase + 2]);
            float B1 = b1[vx], B2 = b2[vx]; int I = bi[vx];
            if (ob1 > B1) { B2 = fmaxf(B1, ob2); B1 = ob1; I = oi; }
            else          { B2 = fmaxf(B2, ob1); }

            const int v = (blk << 7) + vloc;
            if (B1 - B2 <= SMARGIN) {
                if (dg == 0) { const int p = atomicAdd(flagcnt, 1); flagids[p] = v; }
            } else {
                const float* eq = emb + I * DIM + dg * 16;
                float* op = out + ((size_t)b << 19) + toff + vx * 16;
                #pragma unroll
                for (int j = 0; j < 16; j++) {
                    const float xf = xv[vx][j];
                    op[(size_t)(dg * 16 + j) << 13] = xf + (eq[j] - xf);
                }
                if (dg == 0) atomicAdd(&counts[I], 1);
                float* dwp = dw + I * DIM + dg * 16;
                #pragma unroll
                for (int j = 0; j < 16; j++) atomicAdd(&dwp[j], xv[vx][j]);
            }
        }
    }
}

// ---------------- rescan: one block per flagged vector, exact fp64 ----------
__global__ __launch_bounds__(256) void vq_rescan(const float* __restrict__ x,
                                                 const float* __restrict__ emb,
                                                 const double* __restrict__ e64,
                                                 const double* __restrict__ snh64,
                                                 float* __restrict__ out,
                                                 float* __restrict__ dw,
                                                 int* __restrict__ counts,
                                                 const int* __restrict__ flagcnt,
                                                 const int* __restrict__ flagids) {
    __shared__ double sb[256];
    __shared__ int    si[256];
    const int tid   = threadIdx.x;
    const int cslot = tid >> 2;          // 0..63 code slot (block-wide)
    const int dg    = tid & 3;           // 16-dim group
    const int count = *flagcnt;

    for (int i = blockIdx.x; i < count; i += gridDim.x) {
        const int v = flagids[i];
        const int b = v >> 13, t = v & (T_ - 1);
        const float* xb = x + ((size_t)b << 19) + t;

        double xd[16];
        #pragma unroll
        for (int j = 0; j < 16; j++) xd[j] = (double)xb[(size_t)(dg * 16 + j) << 13];

        double best = -1e300; int bi_ = 0;
        for (int cc = 0; cc < 16; cc++) {
            const int k = cc * 64 + cslot;
            const double* ek = e64 + (size_t)k * DIM + dg * 16;
            double a = 0.0;
            #pragma unroll
            for (int j = 0; j < 16; j++) a = __fma_rn(xd[j], ek[j], a);
            a += __shfl_xor(a, 1, 64);
            a += __shfl_xor(a, 2, 64);   // full dot across 4 dim-groups
            const double m = a - snh64[k];
            if (m > best) { best = m; bi_ = k; }  // ascending k: first-max kept
        }

        __syncthreads();                 // protect sb/si from previous iteration
        sb[tid] = best; si[tid] = bi_;
        __syncthreads();
        for (int s = 128; s > 0; s >>= 1) {
            if (tid < s) {
                const double ob = sb[tid + s]; const int oi = si[tid + s];
                if (ob > sb[tid] || (ob == sb[tid] && oi < si[tid])) {
                    sb[tid] = ob; si[tid] = oi;
                }
            }
            __syncthreads();
        }
        const int I = si[0];

        if (tid < 64) {                  // epilogue: thread = dim
            const float xf = xb[(size_t)tid << 13];
            out[((size_t)b << 19) + ((size_t)tid << 13) + t] = xf + (emb[I * DIM + tid] - xf);
            atomicAdd(&dw[I * DIM + tid], xf);
            if (tid == 0) atomicAdd(&counts[I], 1);
        }
    }
}

// ---------------- finalize: new_embeddings = dw / cluster_size --------------
__global__ __launch_bounds__(64) void vq_final(const float* __restrict__ dw,
                                               const int* __restrict__ counts,
                                               float* __restrict__ newemb) {
    const int k = blockIdx.x;
    const int d = threadIdx.x;
    const float c = (float)counts[k];
    const float n = 131072.0f;
    const float cluster = (c + EPSF) / (n + 1024.0f * EPSF) * n;
    newemb[k * DIM + d] = dw[k * DIM + d] / cluster;
}

extern "C" void kernel_launch(void* const* d_in, const int* in_sizes, int n_in,
                              void* d_out, int out_size, void* d_ws, size_t ws_size,
                              hipStream_t stream) {
    const float* x   = (const float*)d_in[0];
    const float* emb = (const float*)d_in[1];

    char* ws = (char*)d_ws;
    double* e64     = (double*)(ws);                 // 524288 B
    double* snh64   = (double*)(ws + 524288);        //   8192 B
    float*  snh32   = (float*)(ws + 532480);         //   4096 B
    float*  dw      = (float*)(ws + 536576);         // 262144 B
    int*    counts  = (int*)(ws + 798720);           //   4096 B
    int*    flagcnt = (int*)(ws + 802816);           //     64 B
    int*    flagids = (int*)(ws + 802880);           // 524288 B

    float* out    = (float*)d_out;
    float* newemb = out + (size_t)B_ * DIM * T_;

    // zero dw + counts + flagcnt (contiguous) every launch
    hipMemsetAsync(dw, 0, 262144 + 4096 + 64, stream);

    vq_prep<<<K_CODES, 64, 0, stream>>>(emb, e64, snh64, snh32);
    vq_screen<<<N_ / 128, 256, 0, stream>>>(x, emb, snh32, out, dw, counts,
                                            flagcnt, flagids);
    vq_rescan<<<512, 256, 0, stream>>>(x, emb, e64, snh64, out, dw, counts,
                                       flagcnt, flagids);
    vq_final<<<K_CODES, 64, 0, stream>>>(dw, counts, newemb);
}